// Round 7
// baseline (1673.148 us; speedup 1.0000x reference)
//
#include <hip/hip_runtime.h>
#include <hip/hip_bf16.h>

#define HW_ 17
#define P_ 289            // 17*17
#define BIMG 128
#define CIN 256
#define CHID 1024

// ---- workspace layout (bytes) ----
#define WS_S_OFF    1024           // 128*289*4 f32 accumulator for s
#define WS_W2_OFF   262144         // 9*1024*512*2 = 9437184
#define WS_X2_OFF   9699328        // 128*289*512*2 = 37879808

typedef __attribute__((ext_vector_type(8))) short short8;
typedef __attribute__((ext_vector_type(4))) float float4_t;

__device__ __forceinline__ unsigned short f32_to_bf16_rne(float f) {
  unsigned int u = __builtin_bit_cast(unsigned int, f);
  unsigned int r = (u + 0x7FFFu + ((u >> 16) & 1u)) >> 16;
  return (unsigned short)r;
}
__device__ __forceinline__ float bf16_bits_to_f32(unsigned short h) {
  unsigned int u = ((unsigned int)h) << 16;
  return __builtin_bit_cast(float, u);
}
__device__ __forceinline__ void glds16(const void* g, void* l) {
  __builtin_amdgcn_global_load_lds(
      (const __attribute__((address_space(1))) void*)g,
      (__attribute__((address_space(3))) void*)l, 16, 0, 0);
}

// ---- prep: w_rnn [1024][256][3][3] f32 -> w2 [9][1024][512] bf16 (hi|lo) ----
__global__ void prep_w_kernel(const float* __restrict__ w_rnn,
                              unsigned short* __restrict__ w2) {
  int t = blockIdx.x * 256 + threadIdx.x;   // 9*1024*256 total
  int c = t & 255;
  int oc = (t >> 8) & 1023;
  int kyx = t >> 18;                        // 0..8
  float w = w_rnn[(size_t)(oc * 256 + c) * 9 + kyx];
  unsigned short hi = f32_to_bf16_rne(w);
  unsigned short lo = f32_to_bf16_rne(w - bf16_bits_to_f32(hi));
  size_t base = (size_t)(kyx * 1024 + oc) * 512;
  w2[base + c] = hi;
  w2[base + 256 + c] = lo;
}

// ---- prep: x [128][256][17][17] f32 -> x2 [n][p][512] bf16 (hi|lo) ----
__global__ void prep_x_kernel(const float* __restrict__ x,
                              unsigned short* __restrict__ x2) {
  __shared__ unsigned short hibuf[P_ * 34];
  __shared__ unsigned short lobuf[P_ * 34];
  int n = blockIdx.y;
  int c0 = blockIdx.x * 32;
  int t = threadIdx.x;  // 256
  for (int ci = 0; ci < 32; ++ci) {
    const float* src = x + (size_t)(n * CIN + c0 + ci) * P_;
    for (int pb = 0; pb < 2; ++pb) {
      int p = pb * 256 + t;
      if (p < P_) {
        float v = src[p];
        unsigned short h = f32_to_bf16_rne(v);
        hibuf[p * 34 + ci] = h;
        lobuf[p * 34 + ci] = f32_to_bf16_rne(v - bf16_bits_to_f32(h));
      }
    }
  }
  __syncthreads();
  int ci = t & 31;
  int psub = t >> 5;  // 0..7
  for (int pb = 0; pb < P_; pb += 8) {
    int p = pb + psub;
    if (p < P_) {
      size_t ob = ((size_t)n * P_ + p) * 512;
      x2[ob + c0 + ci]       = hibuf[p * 34 + ci];
      x2[ob + 256 + c0 + ci] = lobuf[p * 34 + ci];
    }
  }
}

// ---- conv: implicit GEMM ----
// B (x2) halo 19x19 resident in 48KB LDS per 64-ch segment, f=(hy+hx)&7 swizzle
//   (wrap-proof: (py+px) mod 8 increments by exactly 1 along pixel order, so every
//    8-lane ds_read phase is a perfect bank permutation for every tap shift).
// A (w2) loaded global->VGPR per fragment (L2-resident, 16B contiguous).
// Barriers only at segment boundaries (2 per segment, 16 total); taps free-run.
// grid (8 mb, 128 n), 256 threads = 4 waves (2M x 2N), wave tile 64 oc x 160 pos.
__global__ __launch_bounds__(256, 2) void conv_kernel(
    const unsigned short* __restrict__ w2,   // [9][1024][512]
    const unsigned short* __restrict__ x2,   // [128*289][512]
    const float* __restrict__ b_rnn,
    const float* __restrict__ w_out,
    const char* __restrict__ zpage,
    float* __restrict__ sbuf) {
  __shared__ char lds[49152];                // 384 halo rows * 128 B
  const int t = threadIdx.x;
  const int n = blockIdx.y;
  const int oc0 = blockIdx.x * 128;

  const int lane = t & 63;
  const int wid = t >> 6;
  const int wm = wid >> 1, wn = wid & 1;
  const int lrow = lane & 15, g = lane >> 4;

  // ---------- halo staging geometry ----------
  const int cc = t & 7;            // 16B unit within 128B row
  const int rr = t >> 3;           // 0..31 row within a 32-row issue group
  const char* x2c = (const char*)x2;
  int pOff[12];
#pragma unroll
  for (int i = 0; i < 12; ++i) {
    int h = i * 32 + rr;                 // halo row staged by this lane
    int hy = h / 19, hx = h - hy * 19;
    int f = (hy + hx) & 7;
    int sw = cc ^ f;                     // inverse-swizzled source chunk
    bool interior = (h < 361) && (hy >= 1) && (hy <= 17) && (hx >= 1) && (hx <= 17);
    int p = (hy - 1) * 17 + (hx - 1);
    pOff[i] = interior ? (int)(((size_t)(n * P_ + p)) * 1024 + sw * 16) : -1;
  }

  // ---------- A (weights) global-load geometry ----------
  const char* w2b = (const char*)w2 + (size_t)oc0 * 1024;
  int avoff[4];
#pragma unroll
  for (int i = 0; i < 4; ++i)
    avoff[i] = (wm * 64 + i * 16 + lrow) * 1024 + g * 16;

  // ---------- B read geometry ----------
  int hb128[10], fbs[10];
#pragma unroll
  for (int j = 0; j < 10; ++j) {
    int p = wn * 160 + j * 16 + lrow;
    if (p < P_) {
      int py = p / 17, px = p - py * 17;
      hb128[j] = (py * 19 + px) * 128;
      fbs[j] = (py + px) & 7;
    } else {
      hb128[j] = 0;
      fbs[j] = 0;
    }
  }
  const int Cg = g * 16;

  float4_t acc[4][10];
#pragma unroll
  for (int i = 0; i < 4; ++i)
#pragma unroll
    for (int j = 0; j < 10; ++j) acc[i][j] = (float4_t){0.f, 0.f, 0.f, 0.f};

  // one tap-step: A fragments from global (L2), B fragments from swizzled halo
  auto step = [&](int tap, const char* aBase) {
    short8 af[4][2];
#pragma unroll
    for (int i = 0; i < 4; ++i)
#pragma unroll
      for (int kk = 0; kk < 2; ++kk)
        af[i][kk] = *(const short8*)(aBase + avoff[i] + kk * 64);
    const int dy = tap / 3, dx = tap - 3 * (tap / 3);
    const int d128 = (dy * 19 + dx) * 128;
    const int fd = dy + dx;
    int ba[10];
#pragma unroll
    for (int j = 0; j < 10; ++j)
      ba[j] = hb128[j] + d128 + (Cg ^ (((fbs[j] + fd) & 7) << 4));
    __builtin_amdgcn_s_setprio(1);
#pragma unroll
    for (int kk = 0; kk < 2; ++kk) {
#pragma unroll
      for (int jh = 0; jh < 2; ++jh) {
        short8 bf[5];
#pragma unroll
        for (int j5 = 0; j5 < 5; ++j5)
          bf[j5] = *(const short8*)(lds + (ba[jh * 5 + j5] ^ (kk * 64)));
#pragma unroll
        for (int i = 0; i < 4; ++i)
#pragma unroll
          for (int j5 = 0; j5 < 5; ++j5)
            acc[i][jh * 5 + j5] = __builtin_amdgcn_mfma_f32_16x16x32_bf16(
                af[i][kk], bf[j5], acc[i][jh * 5 + j5], 0, 0, 0);
      }
    }
    __builtin_amdgcn_s_setprio(0);
  };

  // 8 segments: seg 0..3 = x-hi chunks (A: {hi, lo}), seg 4..7 = x-lo chunks (A: {hi})
  for (int seg = 0; seg < 8; ++seg) {
    __syncthreads();   // all waves done reading previous halo
#pragma unroll
    for (int i = 0; i < 12; ++i) {
      const char* src = (pOff[i] >= 0) ? x2c + (size_t)pOff[i] + seg * 128 : zpage;
      glds16(src, lds + wid * 1024 + i * 4096);
    }
    __syncthreads();   // waits vmcnt(0): halo ready
    if (seg < 4) {
#pragma unroll
      for (int tap = 0; tap < 9; ++tap)
        step(tap, w2b + (size_t)tap * 1048576 + seg * 128);          // w_hi * x_hi
#pragma unroll
      for (int tap = 0; tap < 9; ++tap)
        step(tap, w2b + (size_t)tap * 1048576 + seg * 128 + 512);    // w_lo * x_hi
    } else {
#pragma unroll
      for (int tap = 0; tap < 9; ++tap)
        step(tap, w2b + (size_t)tap * 1048576 + (seg - 4) * 128);    // w_hi * x_lo
    }
  }

  // ---------- epilogue: +b_rnn, tanh, relu, dot w_out, reduce, atomic ----------
  float sacc[10] = {0.f, 0.f, 0.f, 0.f, 0.f, 0.f, 0.f, 0.f, 0.f, 0.f};
#pragma unroll
  for (int i = 0; i < 4; ++i) {
#pragma unroll
    for (int r = 0; r < 4; ++r) {
      int oc = oc0 + wm * 64 + i * 16 + g * 4 + r;
      float wo = w_out[oc];
      float br = b_rnn[oc];
#pragma unroll
      for (int j = 0; j < 10; ++j) {
        float v = acc[i][j][r] + br;
        float h = tanhf(v);
        h = fmaxf(h, 0.f);
        sacc[j] = fmaf(wo, h, sacc[j]);
      }
    }
  }
#pragma unroll
  for (int j = 0; j < 10; ++j) {
    sacc[j] += __shfl_xor(sacc[j], 16);
    sacc[j] += __shfl_xor(sacc[j], 32);
  }
  if (lane < 16) {
#pragma unroll
    for (int j = 0; j < 10; ++j) {
      int pos = wn * 160 + j * 16 + lrow;
      if (pos < P_) atomicAdd(&sbuf[n * P_ + pos], sacc[j]);
    }
  }
}

// ---- finalize: sigmoid + write score + first-occurrence argmax -> (y,x) floats ----
__global__ void finalize_kernel(const float* __restrict__ sbuf,
                                const float* __restrict__ b_out,
                                float* __restrict__ out) {
  int n = blockIdx.x;
  int lane = threadIdx.x;  // 64
  float bo = b_out[0];
  float vmax = -1e30f;
  int imax = 0x7FFFFFFF;
  for (int p = lane; p < P_; p += 64) {
    float v = sbuf[n * P_ + p] + bo;
    float sg = 1.0f / (1.0f + expf(-v));
    out[n * P_ + p] = sg;
    if (sg > vmax) { vmax = sg; imax = p; }  // strict > keeps first occurrence
  }
  for (int off = 32; off >= 1; off >>= 1) {
    float ov = __shfl_xor(vmax, off);
    int oi = __shfl_xor(imax, off);
    if (ov > vmax || (ov == vmax && oi < imax)) { vmax = ov; imax = oi; }
  }
  if (lane == 0) {
    int y = imax / 17;
    int xq = imax - y * 17;
    out[BIMG * P_ + n * 2 + 0] = (float)y;
    out[BIMG * P_ + n * 2 + 1] = (float)xq;
  }
}

extern "C" void kernel_launch(void* const* d_in, const int* in_sizes, int n_in,
                              void* d_out, int out_size, void* d_ws, size_t ws_size,
                              hipStream_t stream) {
  const float* x     = (const float*)d_in[0];
  const float* w_rnn = (const float*)d_in[1];
  const float* b_rnn = (const float*)d_in[2];
  const float* w_out = (const float*)d_in[3];
  const float* b_out = (const float*)d_in[4];
  char* ws = (char*)d_ws;
  unsigned short* w2 = (unsigned short*)(ws + WS_W2_OFF);
  unsigned short* x2 = (unsigned short*)(ws + WS_X2_OFF);
  float* sbuf = (float*)(ws + WS_S_OFF);
  float* out = (float*)d_out;

  // zero page + s accumulator (ws is re-poisoned to 0xAA before every launch)
  hipMemsetAsync(ws, 0, WS_S_OFF + BIMG * P_ * 4, stream);
  prep_w_kernel<<<9216, 256, 0, stream>>>(w_rnn, w2);
  prep_x_kernel<<<dim3(8, 128), 256, 0, stream>>>(x, x2);
  conv_kernel<<<dim3(8, 128), 256, 0, stream>>>(w2, x2, b_rnn, w_out, ws, sbuf);
  finalize_kernel<<<128, 64, 0, stream>>>(sbuf, b_out, out);
}

// Round 11
// 1148.976 us; speedup vs baseline: 1.4562x; 1.4562x over previous
//
#include <hip/hip_runtime.h>
#include <hip/hip_bf16.h>

#define HW_ 17
#define P_ 289            // 17*17
#define BIMG 128
#define CIN 256
#define CHID 1024

// ---- workspace layout (bytes) ----
#define WS_S_OFF    1024           // 128*289*4 f32 accumulator for s
#define WS_W2_OFF   262144         // 9*1024*512*2 = 9437184
#define WS_X2_OFF   9699328        // 128*289*512*2 = 37879808

typedef __attribute__((ext_vector_type(8))) short short8;
typedef __attribute__((ext_vector_type(4))) float float4_t;

__device__ __forceinline__ unsigned short f32_to_bf16_rne(float f) {
  unsigned int u = __builtin_bit_cast(unsigned int, f);
  unsigned int r = (u + 0x7FFFu + ((u >> 16) & 1u)) >> 16;
  return (unsigned short)r;
}
__device__ __forceinline__ float bf16_bits_to_f32(unsigned short h) {
  unsigned int u = ((unsigned int)h) << 16;
  return __builtin_bit_cast(float, u);
}
__device__ __forceinline__ void glds16(const void* g, void* l) {
  __builtin_amdgcn_global_load_lds(
      (const __attribute__((address_space(1))) void*)g,
      (__attribute__((address_space(3))) void*)l, 16, 0, 0);
}

// ---- prep: w_rnn [1024][256][3][3] f32 -> w2 [9][1024][512] bf16 (hi|lo) ----
__global__ void prep_w_kernel(const float* __restrict__ w_rnn,
                              unsigned short* __restrict__ w2) {
  int t = blockIdx.x * 256 + threadIdx.x;   // 9*1024*256 total
  int c = t & 255;
  int oc = (t >> 8) & 1023;
  int kyx = t >> 18;                        // 0..8
  float w = w_rnn[(size_t)(oc * 256 + c) * 9 + kyx];
  unsigned short hi = f32_to_bf16_rne(w);
  unsigned short lo = f32_to_bf16_rne(w - bf16_bits_to_f32(hi));
  size_t base = (size_t)(kyx * 1024 + oc) * 512;
  w2[base + c] = hi;
  w2[base + 256 + c] = lo;
}

// ---- prep: x [128][256][17][17] f32 -> x2 [n][p][512] bf16 (hi|lo) ----
__global__ void prep_x_kernel(const float* __restrict__ x,
                              unsigned short* __restrict__ x2) {
  __shared__ unsigned short hibuf[P_ * 34];
  __shared__ unsigned short lobuf[P_ * 34];
  int n = blockIdx.y;
  int c0 = blockIdx.x * 32;
  int t = threadIdx.x;  // 256
  for (int ci = 0; ci < 32; ++ci) {
    const float* src = x + (size_t)(n * CIN + c0 + ci) * P_;
    for (int pb = 0; pb < 2; ++pb) {
      int p = pb * 256 + t;
      if (p < P_) {
        float v = src[p];
        unsigned short h = f32_to_bf16_rne(v);
        hibuf[p * 34 + ci] = h;
        lobuf[p * 34 + ci] = f32_to_bf16_rne(v - bf16_bits_to_f32(h));
      }
    }
  }
  __syncthreads();
  int ci = t & 31;
  int psub = t >> 5;  // 0..7
  for (int pb = 0; pb < P_; pb += 8) {
    int p = pb + psub;
    if (p < P_) {
      size_t ob = ((size_t)n * P_ + p) * 512;
      x2[ob + c0 + ci]       = hibuf[p * 34 + ci];
      x2[ob + 256 + c0 + ci] = lobuf[p * 34 + ci];
    }
  }
}

// ---- conv: implicit GEMM ----
// B (x2) halo 19x19 in 48KB LDS per 64-ch segment, f=(hy+hx)&7 wrap-proof swizzle.
// A (w2) global->VGPR per kk (L1/L2-resident). Barriers only at segment bounds.
// grid (8 mb, 2 nb, 128 n), 256 threads = 4 waves (2M x 2N), wave tile 64oc x 80pos.
// acc[4][5]=80 regs -> total live ~160, no spill (round-7 lesson: 64x160 spilled).
__global__ __launch_bounds__(256, 2) void conv_kernel(
    const unsigned short* __restrict__ w2,   // [9][1024][512]
    const unsigned short* __restrict__ x2,   // [128*289][512]
    const float* __restrict__ b_rnn,
    const float* __restrict__ w_out,
    const char* __restrict__ zpage,
    float* __restrict__ sbuf) {
  __shared__ char lds[49152];                // 384 halo rows * 128 B
  const int t = threadIdx.x;
  const int n = blockIdx.z;
  const int nb = blockIdx.y;
  const int oc0 = blockIdx.x * 128;

  const int lane = t & 63;
  const int wid = t >> 6;
  const int wm = wid >> 1, wn = wid & 1;
  const int lrow = lane & 15, g = lane >> 4;

  // ---------- halo staging geometry ----------
  const int cc = t & 7;            // 16B unit within 128B row
  const int rr = t >> 3;           // 0..31 row within a 32-row issue group
  const char* x2c = (const char*)x2;
  int pOff[12];
#pragma unroll
  for (int i = 0; i < 12; ++i) {
    int h = i * 32 + rr;                 // halo row staged by this lane
    int hy = h / 19, hx = h - hy * 19;
    int f = (hy + hx) & 7;
    int sw = cc ^ f;                     // inverse-swizzled source chunk
    bool interior = (h < 361) && (hy >= 1) && (hy <= 17) && (hx >= 1) && (hx <= 17);
    int p = (hy - 1) * 17 + (hx - 1);
    pOff[i] = interior ? (int)(((size_t)(n * P_ + p)) * 1024 + sw * 16) : -1;
  }
  // nb=0 reads halo rows 0..227 (issues 0..7); nb=1 reads rows 171..360 (issues 5..11)
  const int iLo = nb ? 5 : 0;
  const int iHi = nb ? 12 : 8;

  // ---------- A (weights) global-load geometry ----------
  const char* w2b = (const char*)w2 + (size_t)oc0 * 1024;
  int avoff[4];
#pragma unroll
  for (int i = 0; i < 4; ++i)
    avoff[i] = (wm * 64 + i * 16 + lrow) * 1024 + g * 16;

  // ---------- B read geometry (wave covers 80 pos) ----------
  int hb128[5], fbs[5];
#pragma unroll
  for (int j = 0; j < 5; ++j) {
    int p = nb * 160 + wn * 80 + j * 16 + lrow;
    if (p < P_) {
      int py = p / 17, px = p - py * 17;
      hb128[j] = (py * 19 + px) * 128;
      fbs[j] = (py + px) & 7;
    } else {
      hb128[j] = 0;
      fbs[j] = 0;
    }
  }
  const int Cg = g * 16;

  float4_t acc[4][5];
#pragma unroll
  for (int i = 0; i < 4; ++i)
#pragma unroll
    for (int j = 0; j < 5; ++j) acc[i][j] = (float4_t){0.f, 0.f, 0.f, 0.f};

  // one tap-step: A fragments from global (L1/L2), B fragments from swizzled halo
  auto step = [&](int tap, const char* aBase) {
    const int dy = tap / 3, dx = tap - 3 * (tap / 3);
    const int d128 = (dy * 19 + dx) * 128;
    const int fd = dy + dx;
    int ba[5];
#pragma unroll
    for (int j = 0; j < 5; ++j)
      ba[j] = hb128[j] + d128 + (Cg ^ (((fbs[j] + fd) & 7) << 4));
    __builtin_amdgcn_s_setprio(1);
#pragma unroll
    for (int kk = 0; kk < 2; ++kk) {
      short8 af[4];
#pragma unroll
      for (int i = 0; i < 4; ++i)
        af[i] = *(const short8*)(aBase + avoff[i] + kk * 64);
      short8 bf[5];
#pragma unroll
      for (int j = 0; j < 5; ++j)
        bf[j] = *(const short8*)(lds + (ba[j] ^ (kk * 64)));
#pragma unroll
      for (int i = 0; i < 4; ++i)
#pragma unroll
        for (int j = 0; j < 5; ++j)
          acc[i][j] = __builtin_amdgcn_mfma_f32_16x16x32_bf16(
              af[i], bf[j], acc[i][j], 0, 0, 0);
    }
    __builtin_amdgcn_s_setprio(0);
  };

  // 8 segments: seg 0..3 = x-hi chunks (A: {hi, lo}), seg 4..7 = x-lo chunks (A: {hi})
  for (int seg = 0; seg < 8; ++seg) {
    __syncthreads();   // all waves done reading previous halo
    for (int i = iLo; i < iHi; ++i) {
      const char* src = (pOff[i] >= 0) ? x2c + (size_t)pOff[i] + seg * 128 : zpage;
      glds16(src, lds + wid * 1024 + i * 4096);
    }
    __syncthreads();   // implies vmcnt(0): halo ready
    if (seg < 4) {
#pragma unroll
      for (int tap = 0; tap < 9; ++tap)
        step(tap, w2b + (size_t)tap * 1048576 + seg * 128);          // w_hi * x_hi
#pragma unroll
      for (int tap = 0; tap < 9; ++tap)
        step(tap, w2b + (size_t)tap * 1048576 + seg * 128 + 512);    // w_lo * x_hi
    } else {
#pragma unroll
      for (int tap = 0; tap < 9; ++tap)
        step(tap, w2b + (size_t)tap * 1048576 + (seg - 4) * 128);    // w_hi * x_lo
    }
  }

  // ---------- epilogue: +b_rnn, tanh, relu, dot w_out, reduce, atomic ----------
  float sacc[5] = {0.f, 0.f, 0.f, 0.f, 0.f};
#pragma unroll
  for (int i = 0; i < 4; ++i) {
#pragma unroll
    for (int r = 0; r < 4; ++r) {
      int oc = oc0 + wm * 64 + i * 16 + g * 4 + r;
      float wo = w_out[oc];
      float br = b_rnn[oc];
#pragma unroll
      for (int j = 0; j < 5; ++j) {
        float v = acc[i][j][r] + br;
        float h = tanhf(v);
        h = fmaxf(h, 0.f);
        sacc[j] = fmaf(wo, h, sacc[j]);
      }
    }
  }
#pragma unroll
  for (int j = 0; j < 5; ++j) {
    sacc[j] += __shfl_xor(sacc[j], 16);
    sacc[j] += __shfl_xor(sacc[j], 32);
  }
  if (lane < 16) {
#pragma unroll
    for (int j = 0; j < 5; ++j) {
      int pos = nb * 160 + wn * 80 + j * 16 + lrow;
      if (pos < P_) atomicAdd(&sbuf[n * P_ + pos], sacc[j]);
    }
  }
}

// ---- finalize: sigmoid + write score + first-occurrence argmax -> (y,x) floats ----
__global__ void finalize_kernel(const float* __restrict__ sbuf,
                                const float* __restrict__ b_out,
                                float* __restrict__ out) {
  int n = blockIdx.x;
  int lane = threadIdx.x;  // 64
  float bo = b_out[0];
  float vmax = -1e30f;
  int imax = 0x7FFFFFFF;
  for (int p = lane; p < P_; p += 64) {
    float v = sbuf[n * P_ + p] + bo;
    float sg = 1.0f / (1.0f + expf(-v));
    out[n * P_ + p] = sg;
    if (sg > vmax) { vmax = sg; imax = p; }  // strict > keeps first occurrence
  }
  for (int off = 32; off >= 1; off >>= 1) {
    float ov = __shfl_xor(vmax, off);
    int oi = __shfl_xor(imax, off);
    if (ov > vmax || (ov == vmax && oi < imax)) { vmax = ov; imax = oi; }
  }
  if (lane == 0) {
    int y = imax / 17;
    int xq = imax - y * 17;
    out[BIMG * P_ + n * 2 + 0] = (float)y;
    out[BIMG * P_ + n * 2 + 1] = (float)xq;
  }
}

extern "C" void kernel_launch(void* const* d_in, const int* in_sizes, int n_in,
                              void* d_out, int out_size, void* d_ws, size_t ws_size,
                              hipStream_t stream) {
  const float* x     = (const float*)d_in[0];
  const float* w_rnn = (const float*)d_in[1];
  const float* b_rnn = (const float*)d_in[2];
  const float* w_out = (const float*)d_in[3];
  const float* b_out = (const float*)d_in[4];
  char* ws = (char*)d_ws;
  unsigned short* w2 = (unsigned short*)(ws + WS_W2_OFF);
  unsigned short* x2 = (unsigned short*)(ws + WS_X2_OFF);
  float* sbuf = (float*)(ws + WS_S_OFF);
  float* out = (float*)d_out;

  // zero page + s accumulator (ws is re-poisoned to 0xAA before every launch)
  hipMemsetAsync(ws, 0, WS_S_OFF + BIMG * P_ * 4, stream);
  prep_w_kernel<<<9216, 256, 0, stream>>>(w_rnn, w2);
  prep_x_kernel<<<dim3(8, 128), 256, 0, stream>>>(x, x2);
  conv_kernel<<<dim3(8, 2, 128), 256, 0, stream>>>(w2, x2, b_rnn, w_out, ws, sbuf);
  finalize_kernel<<<128, 64, 0, stream>>>(sbuf, b_out, out);
}

// Round 12
// 1050.433 us; speedup vs baseline: 1.5928x; 1.0938x over previous
//
#include <hip/hip_runtime.h>
#include <hip/hip_bf16.h>

#define HW_ 17
#define P_ 289            // 17*17
#define BIMG 128
#define CIN 256
#define CHID 1024

// ---- workspace layout (bytes) ----
#define WS_S_OFF    1024           // 128*289*4 f32 accumulator for s
#define WS_W2_OFF   262144         // 9*1024*512*2 = 9437184
#define WS_X2_OFF   9699328        // 128*289*512*2 = 37879808

typedef __attribute__((ext_vector_type(8))) short short8;
typedef __attribute__((ext_vector_type(4))) float float4_t;

__device__ __forceinline__ unsigned short f32_to_bf16_rne(float f) {
  unsigned int u = __builtin_bit_cast(unsigned int, f);
  unsigned int r = (u + 0x7FFFu + ((u >> 16) & 1u)) >> 16;
  return (unsigned short)r;
}
__device__ __forceinline__ float bf16_bits_to_f32(unsigned short h) {
  unsigned int u = ((unsigned int)h) << 16;
  return __builtin_bit_cast(float, u);
}
__device__ __forceinline__ void glds16(const void* g, void* l) {
  __builtin_amdgcn_global_load_lds(
      (const __attribute__((address_space(1))) void*)g,
      (__attribute__((address_space(3))) void*)l, 16, 0, 0);
}

// ---- prep: w_rnn [1024][256][3][3] f32 -> w2 [9][1024][512] bf16 (hi|lo) ----
__global__ void prep_w_kernel(const float* __restrict__ w_rnn,
                              unsigned short* __restrict__ w2) {
  int t = blockIdx.x * 256 + threadIdx.x;   // 9*1024*256 total
  int c = t & 255;
  int oc = (t >> 8) & 1023;
  int kyx = t >> 18;                        // 0..8
  float w = w_rnn[(size_t)(oc * 256 + c) * 9 + kyx];
  unsigned short hi = f32_to_bf16_rne(w);
  unsigned short lo = f32_to_bf16_rne(w - bf16_bits_to_f32(hi));
  size_t base = (size_t)(kyx * 1024 + oc) * 512;
  w2[base + c] = hi;
  w2[base + 256 + c] = lo;
}

// ---- prep: x [128][256][17][17] f32 -> x2 [n][p][512] bf16 (hi|lo) ----
__global__ void prep_x_kernel(const float* __restrict__ x,
                              unsigned short* __restrict__ x2) {
  __shared__ unsigned short hibuf[P_ * 34];
  __shared__ unsigned short lobuf[P_ * 34];
  int n = blockIdx.y;
  int c0 = blockIdx.x * 32;
  int t = threadIdx.x;  // 256
  for (int ci = 0; ci < 32; ++ci) {
    const float* src = x + (size_t)(n * CIN + c0 + ci) * P_;
    for (int pb = 0; pb < 2; ++pb) {
      int p = pb * 256 + t;
      if (p < P_) {
        float v = src[p];
        unsigned short h = f32_to_bf16_rne(v);
        hibuf[p * 34 + ci] = h;
        lobuf[p * 34 + ci] = f32_to_bf16_rne(v - bf16_bits_to_f32(h));
      }
    }
  }
  __syncthreads();
  int ci = t & 31;
  int psub = t >> 5;  // 0..7
  for (int pb = 0; pb < P_; pb += 8) {
    int p = pb + psub;
    if (p < P_) {
      size_t ob = ((size_t)n * P_ + p) * 512;
      x2[ob + c0 + ci]       = hibuf[p * 34 + ci];
      x2[ob + 256 + c0 + ci] = lobuf[p * 34 + ci];
    }
  }
}

// ---- conv: implicit GEMM ----
// B (x2) halo 19x19 in 48KB LDS per 64-ch segment, f=(hy+hx)&7 wrap-proof swizzle.
// A (w2) global->VGPR, 16 frags batched per tap (seg<4 fuses hi+lo products: 80
// MFMAs per stall point). __launch_bounds__(256) — no reg cap (round-11 lesson:
// (256,2) caps at 128 arch-VGPRs -> spill + no pipelining). Staging loop unrolled
// with uniform predicate so pOff stays in registers (rule #20).
// grid (8 mb, 2 nb, 128 n), 256 threads = 4 waves (2M x 2N), wave tile 64oc x 80pos.
__global__ __launch_bounds__(256) void conv_kernel(
    const unsigned short* __restrict__ w2,   // [9][1024][512]
    const unsigned short* __restrict__ x2,   // [128*289][512]
    const float* __restrict__ b_rnn,
    const float* __restrict__ w_out,
    const char* __restrict__ zpage,
    float* __restrict__ sbuf) {
  __shared__ char lds[49152];                // 384 halo rows * 128 B
  const int t = threadIdx.x;
  const int n = blockIdx.z;
  const int nb = blockIdx.y;
  const int oc0 = blockIdx.x * 128;

  const int lane = t & 63;
  const int wid = t >> 6;
  const int wm = wid >> 1, wn = wid & 1;
  const int lrow = lane & 15, g = lane >> 4;

  // ---------- halo staging geometry ----------
  const int cc = t & 7;            // 16B unit within 128B row
  const int rr = t >> 3;           // 0..31 row within a 32-row issue group
  const char* x2c = (const char*)x2;
  int pOff[12];
#pragma unroll
  for (int i = 0; i < 12; ++i) {
    int h = i * 32 + rr;                 // halo row staged by this lane
    int hy = h / 19, hx = h - hy * 19;
    int f = (hy + hx) & 7;
    int sw = cc ^ f;                     // inverse-swizzled source chunk
    bool interior = (h < 361) && (hy >= 1) && (hy <= 17) && (hx >= 1) && (hx <= 17);
    int p = (hy - 1) * 17 + (hx - 1);
    pOff[i] = interior ? (int)(((size_t)(n * P_ + p)) * 1024 + sw * 16) : -1;
  }
  // nb=0 needs halo rows <=227 (issues 0..7); nb=1 needs rows >=178 (issues 5..11)
  const int iLo = nb ? 5 : 0;
  const int iHi = nb ? 12 : 8;

  // ---------- A (weights) global-load geometry ----------
  const char* w2b = (const char*)w2 + (size_t)oc0 * 1024;
  int avoff[4];
#pragma unroll
  for (int i = 0; i < 4; ++i)
    avoff[i] = (wm * 64 + i * 16 + lrow) * 1024 + g * 16;

  // ---------- B read geometry (wave covers 80 pos) ----------
  int hb128[5], fbs[5];
#pragma unroll
  for (int j = 0; j < 5; ++j) {
    int p = nb * 160 + wn * 80 + j * 16 + lrow;
    if (p < P_) {
      int py = p / 17, px = p - py * 17;
      hb128[j] = (py * 19 + px) * 128;
      fbs[j] = (py + px) & 7;
    } else {
      hb128[j] = 0;
      fbs[j] = 0;
    }
  }
  const int Cg = g * 16;

  float4_t acc[4][5];
#pragma unroll
  for (int i = 0; i < 4; ++i)
#pragma unroll
    for (int j = 0; j < 5; ++j) acc[i][j] = (float4_t){0.f, 0.f, 0.f, 0.f};

  // one tap-step; HAS_LO fuses the w_lo product (seg<4): 16 A frags, 80 MFMAs.
  auto stepT = [&](int tap, const char* aH, const char* aL, bool hasLo) {
    const int dy = tap / 3, dx = tap - 3 * (tap / 3);
    const int d128 = (dy * 19 + dx) * 128;
    const int fd = dy + dx;
    int ba[5];
#pragma unroll
    for (int j = 0; j < 5; ++j)
      ba[j] = hb128[j] + d128 + (Cg ^ (((fbs[j] + fd) & 7) << 4));
    short8 afh[4][2], afl[4][2];
#pragma unroll
    for (int i = 0; i < 4; ++i)
#pragma unroll
      for (int kk = 0; kk < 2; ++kk)
        afh[i][kk] = *(const short8*)(aH + avoff[i] + kk * 64);
    if (hasLo) {
#pragma unroll
      for (int i = 0; i < 4; ++i)
#pragma unroll
        for (int kk = 0; kk < 2; ++kk)
          afl[i][kk] = *(const short8*)(aL + avoff[i] + kk * 64);
    }
    __builtin_amdgcn_s_setprio(1);
#pragma unroll
    for (int kk = 0; kk < 2; ++kk) {
      short8 bf[5];
#pragma unroll
      for (int j = 0; j < 5; ++j)
        bf[j] = *(const short8*)(lds + (ba[j] ^ (kk * 64)));
#pragma unroll
      for (int i = 0; i < 4; ++i)
#pragma unroll
        for (int j = 0; j < 5; ++j)
          acc[i][j] = __builtin_amdgcn_mfma_f32_16x16x32_bf16(
              afh[i][kk], bf[j], acc[i][j], 0, 0, 0);
      if (hasLo) {
#pragma unroll
        for (int i = 0; i < 4; ++i)
#pragma unroll
          for (int j = 0; j < 5; ++j)
            acc[i][j] = __builtin_amdgcn_mfma_f32_16x16x32_bf16(
                afl[i][kk], bf[j], acc[i][j], 0, 0, 0);
      }
    }
    __builtin_amdgcn_s_setprio(0);
  };

  // 8 segments: seg 0..3 = x-hi chunks (A: hi+lo fused), seg 4..7 = x-lo (A: hi)
  for (int seg = 0; seg < 8; ++seg) {
    __syncthreads();   // all waves done reading previous halo
#pragma unroll
    for (int i = 0; i < 12; ++i) {
      if (i >= iLo && i < iHi) {   // wave-uniform predicate; pOff stays in regs
        const char* src = (pOff[i] >= 0) ? x2c + (size_t)pOff[i] + seg * 128 : zpage;
        glds16(src, lds + wid * 1024 + i * 4096);
      }
    }
    __syncthreads();   // implies vmcnt(0): halo ready
    if (seg < 4) {
#pragma unroll
      for (int tap = 0; tap < 9; ++tap)
        stepT(tap, w2b + (size_t)tap * 1048576 + seg * 128,
                   w2b + (size_t)tap * 1048576 + seg * 128 + 512, true);
    } else {
#pragma unroll
      for (int tap = 0; tap < 9; ++tap)
        stepT(tap, w2b + (size_t)tap * 1048576 + (seg - 4) * 128, nullptr, false);
    }
  }

  // ---------- epilogue: +b_rnn, tanh, relu, dot w_out, reduce, atomic ----------
  float sacc[5] = {0.f, 0.f, 0.f, 0.f, 0.f};
#pragma unroll
  for (int i = 0; i < 4; ++i) {
#pragma unroll
    for (int r = 0; r < 4; ++r) {
      int oc = oc0 + wm * 64 + i * 16 + g * 4 + r;
      float wo = w_out[oc];
      float br = b_rnn[oc];
#pragma unroll
      for (int j = 0; j < 5; ++j) {
        float v = acc[i][j][r] + br;
        float h = tanhf(v);
        h = fmaxf(h, 0.f);
        sacc[j] = fmaf(wo, h, sacc[j]);
      }
    }
  }
#pragma unroll
  for (int j = 0; j < 5; ++j) {
    sacc[j] += __shfl_xor(sacc[j], 16);
    sacc[j] += __shfl_xor(sacc[j], 32);
  }
  if (lane < 16) {
#pragma unroll
    for (int j = 0; j < 5; ++j) {
      int pos = nb * 160 + wn * 80 + j * 16 + lrow;
      if (pos < P_) atomicAdd(&sbuf[n * P_ + pos], sacc[j]);
    }
  }
}

// ---- finalize: sigmoid + write score + first-occurrence argmax -> (y,x) floats ----
__global__ void finalize_kernel(const float* __restrict__ sbuf,
                                const float* __restrict__ b_out,
                                float* __restrict__ out) {
  int n = blockIdx.x;
  int lane = threadIdx.x;  // 64
  float bo = b_out[0];
  float vmax = -1e30f;
  int imax = 0x7FFFFFFF;
  for (int p = lane; p < P_; p += 64) {
    float v = sbuf[n * P_ + p] + bo;
    float sg = 1.0f / (1.0f + expf(-v));
    out[n * P_ + p] = sg;
    if (sg > vmax) { vmax = sg; imax = p; }  // strict > keeps first occurrence
  }
  for (int off = 32; off >= 1; off >>= 1) {
    float ov = __shfl_xor(vmax, off);
    int oi = __shfl_xor(imax, off);
    if (ov > vmax || (ov == vmax && oi < imax)) { vmax = ov; imax = oi; }
  }
  if (lane == 0) {
    int y = imax / 17;
    int xq = imax - y * 17;
    out[BIMG * P_ + n * 2 + 0] = (float)y;
    out[BIMG * P_ + n * 2 + 1] = (float)xq;
  }
}

extern "C" void kernel_launch(void* const* d_in, const int* in_sizes, int n_in,
                              void* d_out, int out_size, void* d_ws, size_t ws_size,
                              hipStream_t stream) {
  const float* x     = (const float*)d_in[0];
  const float* w_rnn = (const float*)d_in[1];
  const float* b_rnn = (const float*)d_in[2];
  const float* w_out = (const float*)d_in[3];
  const float* b_out = (const float*)d_in[4];
  char* ws = (char*)d_ws;
  unsigned short* w2 = (unsigned short*)(ws + WS_W2_OFF);
  unsigned short* x2 = (unsigned short*)(ws + WS_X2_OFF);
  float* sbuf = (float*)(ws + WS_S_OFF);
  float* out = (float*)d_out;

  // zero page + s accumulator (ws is re-poisoned to 0xAA before every launch)
  hipMemsetAsync(ws, 0, WS_S_OFF + BIMG * P_ * 4, stream);
  prep_w_kernel<<<9216, 256, 0, stream>>>(w_rnn, w2);
  prep_x_kernel<<<dim3(8, 128), 256, 0, stream>>>(x, x2);
  conv_kernel<<<dim3(8, 2, 128), 256, 0, stream>>>(w2, x2, b_rnn, w_out, ws, sbuf);
  finalize_kernel<<<128, 64, 0, stream>>>(sbuf, b_out, out);
}